// Round 5
// baseline (97.805 us; speedup 1.0000x reference)
//
#include <hip/hip_runtime.h>
#include <math.h>

constexpr int H  = 4096;
constexpr int H2 = 8192;

__device__ __forceinline__ float dot4s(const float4 w, const float4 v) {
    return fmaf(w.x, v.x, fmaf(w.y, v.y, fmaf(w.z, v.z, w.w * v.w)));
}

// One wave64 per (row, half): 8192 waves -> 2048 blocks -> 8 blocks/CU.
// Spill-proof body: scalar gate accumulators (4 VGPR) + one chunk of 5-6
// float4 loads live per iteration (~24 VGPR) so the 64-VGPR cap of
// launch_bounds(256,8) holds WITHOUT scratch (R2's 22 MB WRITE_SIZE spill
// was unroll-8 hoisting 48 float4; this keeps the live set tiny and lets
// the compiler pipeline what fits).
__global__ __launch_bounds__(256, 8)
void lstm_step_kernel(const float* __restrict__ h_prev,
                      const float* __restrict__ c_prev,
                      const float* __restrict__ x_t,
                      const float* __restrict__ W_f, const float* __restrict__ b_f,
                      const float* __restrict__ W_i, const float* __restrict__ b_i,
                      const float* __restrict__ W_C, const float* __restrict__ b_C,
                      const float* __restrict__ W_o, const float* __restrict__ b_o,
                      float* __restrict__ out)
{
    __shared__ float part[4][4];   // [wave][gate]

    const int wid  = threadIdx.x >> 6;          // 0..3
    const int lane = threadIdx.x & 63;
    const int row  = blockIdx.x * 2 + (wid >> 1);
    const int half = wid & 1;

    const size_t rowbase = (size_t)row * H2;
    const int hoff = half * 1024;               // float4 offset into the row
    const float4* wf = (const float4*)(W_f + rowbase) + hoff;
    const float4* wi = (const float4*)(W_i + rowbase) + hoff;
    const float4* wc = (const float4*)(W_C + rowbase) + hoff;
    const float4* wo = (const float4*)(W_o + rowbase) + hoff;
    const float4* hv = (const float4*)h_prev;
    const float4* xv = (const float4*)x_t;
    const float4* cv = (const float4*)c_prev;

    float sf = 0.f, si = 0.f, sc = 0.f, so = 0.f;

    if (half == 0) {
        // columns [0,H): z = h_prev for all four gates
        for (int it = 0; it < 16; ++it) {
            const int c = it * 64 + lane;       // 0..1023
            const float4 z = hv[c];
            const float4 a = wf[c];
            const float4 b = wi[c];
            const float4 d = wc[c];
            const float4 e = wo[c];
            sf += dot4s(a, z);
            si += dot4s(b, z);
            sc += dot4s(d, z);
            so += dot4s(e, z);
        }
    } else {
        // columns [H,2H): z = x_t for f,i,o ; z = c_prev for C
        for (int it = 0; it < 16; ++it) {
            const int c = it * 64 + lane;       // 0..1023
            const float4 zx = xv[c];
            const float4 zc = cv[c];
            const float4 a = wf[c];
            const float4 b = wi[c];
            const float4 d = wc[c];
            const float4 e = wo[c];
            sf += dot4s(a, zx);
            si += dot4s(b, zx);
            sc += dot4s(d, zc);
            so += dot4s(e, zx);
        }
    }

    #pragma unroll
    for (int off = 32; off > 0; off >>= 1) {
        sf += __shfl_down(sf, off, 64);
        si += __shfl_down(si, off, 64);
        sc += __shfl_down(sc, off, 64);
        so += __shfl_down(so, off, 64);
    }

    if (lane == 0) {
        part[wid][0] = sf;
        part[wid][1] = si;
        part[wid][2] = sc;
        part[wid][3] = so;
    }
    __syncthreads();

    if (threadIdx.x < 2) {
        const int r  = blockIdx.x * 2 + (int)threadIdx.x;
        const int w0 = (int)threadIdx.x * 2;
        const float tf = part[w0][0] + part[w0 + 1][0];
        const float ti = part[w0][1] + part[w0 + 1][1];
        const float tc = part[w0][2] + part[w0 + 1][2];
        const float to = part[w0][3] + part[w0 + 1][3];

        const float f      = 1.f / (1.f + expf(-(tf + b_f[r])));
        const float ig     = 1.f / (1.f + expf(-(ti + b_i[r])));
        const float ctilde = tanhf(tc + b_C[r]);
        const float og     = 1.f / (1.f + expf(-(to + b_o[r])));
        const float Cnew   = f * c_prev[r] + ig * ctilde;
        out[r]     = og * tanhf(Cnew);     // h_t
        out[H + r] = Cnew;                 // C_t
    }
}

extern "C" void kernel_launch(void* const* d_in, const int* in_sizes, int n_in,
                              void* d_out, int out_size, void* d_ws, size_t ws_size,
                              hipStream_t stream) {
    const float* h_prev = (const float*)d_in[0];
    const float* c_prev = (const float*)d_in[1];
    const float* x_t    = (const float*)d_in[2];
    const float* W_f    = (const float*)d_in[3];
    const float* b_f    = (const float*)d_in[4];
    const float* W_i    = (const float*)d_in[5];
    const float* b_i    = (const float*)d_in[6];
    const float* W_C    = (const float*)d_in[7];
    const float* b_C    = (const float*)d_in[8];
    const float* W_o    = (const float*)d_in[9];
    const float* b_o    = (const float*)d_in[10];
    float* out = (float*)d_out;

    // 2 rows per block (4 waves: row0-half0, row0-half1, row1-half0, row1-half1)
    lstm_step_kernel<<<H / 2, 256, 0, stream>>>(
        h_prev, c_prev, x_t, W_f, b_f, W_i, b_i, W_C, b_C, W_o, b_o, out);
}